// Round 9
// baseline (320.496 us; speedup 1.0000x reference)
//
#include <hip/hip_runtime.h>
#include <math.h>

#define B 256
#define N 1152
#define C_ 10
#define OUT 16
#define IN 8
#define KO 160          // C_*OUT

// ---- s-partial geometry: 64-thread (1-wave) blocks, BT=4 rows/thread, all 10 k
#define MB 16           // batch rows per block
#define NC 6            // n per chunk
#define NCH 192         // N/NC
#define XSTR (NC*IN + 4)  // 52 floats: 16B-aligned rows, banks spread

// partial[ch][b][k*16+o] = sum_{n in chunk} c[n,k]*(W[n,k,o,:].x[b,n,:])
// grid 3072 = 8 XCD * 24 ch * 16 bt (bt fastest -> 16 blocks share one 30KB W chunk,
// per-XCD W set 720KB, L2-resident). 12 one-wave blocks/CU = 3 waves/SIMD.
__global__ __launch_bounds__(64, 4) void k_s_partial(
    const float* __restrict__ x, const float* __restrict__ W,
    const float* __restrict__ c, float* __restrict__ partial)
{
    __shared__ float xs[MB][XSTR];      // 3.3 KB
    __shared__ float cs[NC][C_];        // 240 B

    const int tid = threadIdx.x;        // 0..63
    const int id  = blockIdx.x;
    const int g   = id & 7;             // XCD
    const int q   = id >> 3;            // 0..383
    const int bt  = q & 15;             // b-tile fastest on XCD -> W reuse
    const int chl = q >> 4;             // 0..23
    const int ch  = g * 24 + chl;       // 0..191
    const int b0  = bt * MB;
    const int n0  = ch * NC;

    // stage x tile: 16 rows x 12 float4 (48 contiguous floats each)
    for (int idx = tid; idx < MB * (NC * IN / 4); idx += 64) {
        int bl = idx / (NC * IN / 4), r = idx - bl * (NC * IN / 4);
        float4 val = *(const float4*)(x + (size_t)(b0 + bl) * (N * IN) + (size_t)n0 * IN + r * 4);
        *(float4*)(&xs[bl][r * 4]) = val;
    }
    if (c) {
        for (int idx = tid; idx < NC * C_; idx += 64) {
            int nl = idx / C_, k = idx - nl * C_;
            cs[nl][k] = c[(size_t)(n0 + nl) * C_ + k];
        }
    }
    __syncthreads();

    const int o   = tid & 15;
    const int grp = (tid >> 4) * 4;     // rows grp..grp+3

    float acc[4][C_];
#pragma unroll
    for (int r = 0; r < 4; ++r)
#pragma unroll
        for (int k = 0; k < C_; ++k) acc[r][k] = 0.f;

    const float* Wb = W + (size_t)n0 * (KO * IN) + o * IN;

#pragma unroll 2
    for (int nl = 0; nl < NC; ++nl) {
        float4 xr[4][2];
#pragma unroll
        for (int r = 0; r < 4; ++r) {
            xr[r][0] = *(const float4*)(&xs[grp + r][nl * IN]);
            xr[r][1] = *(const float4*)(&xs[grp + r][nl * IN + 4]);
        }
        float cw[C_];
#pragma unroll
        for (int k = 0; k < C_; ++k) cw[k] = c ? cs[nl][k] : 0.1f;

        const float* Wn = Wb + (size_t)nl * (KO * IN);
#pragma unroll
        for (int k = 0; k < C_; ++k) {
            float4 w0 = *(const float4*)(Wn + k * (OUT * IN));
            float4 w1 = *(const float4*)(Wn + k * (OUT * IN) + 4);
#pragma unroll
            for (int r = 0; r < 4; ++r) {
                float d = w0.x * xr[r][0].x + w0.y * xr[r][0].y
                        + w0.z * xr[r][0].z + w0.w * xr[r][0].w
                        + w1.x * xr[r][1].x + w1.y * xr[r][1].y
                        + w1.z * xr[r][1].z + w1.w * xr[r][1].w;
                acc[r][k] += cw[k] * d;
            }
        }
    }

#pragma unroll
    for (int r = 0; r < 4; ++r) {
        float* pp = partial + (size_t)ch * (B * KO) + (size_t)(b0 + grp + r) * KO + o;
#pragma unroll
        for (int k = 0; k < C_; ++k) pp[k * OUT] = acc[r][k];
    }
}

// ---------------- reduce partials over 192 chunks + squash
// grid 640 x 256: block = 64 elements; wave q sums chunks q*48..q*48+47
__global__ __launch_bounds__(256) void k_reduce_squash(
    const float* __restrict__ partial, float* __restrict__ v, float* __restrict__ out)
{
    __shared__ float red[256];
    const int tid = threadIdx.x;
    const int e   = blockIdx.x * 64 + (tid & 63);   // element 0..40959
    const int q   = tid >> 6;                       // wave 0..3
    float s = 0.f;
#pragma unroll
    for (int i = 0; i < NCH / 4; ++i)
        s += partial[(size_t)(q * (NCH / 4) + i) * (B * KO) + e];
    red[tid] = s;
    __syncthreads();
    if (q == 0) {
        s = red[tid] + red[tid + 64] + red[tid + 128] + red[tid + 192];
        float vv = s * fabsf(s) / (1.f + s * s);
        v[e] = vv;
        if (out) out[e] = vv;
    }
}

// ---------------- a-pass (R6 proven version): bij[n][k] (+)= (1/B) sum_{b,o} (W.x)*v
__global__ __launch_bounds__(256) void k_a(
    const float* __restrict__ x, const float* __restrict__ W,
    const float* __restrict__ v, float* __restrict__ bij, int accumulate)
{
    const int n = blockIdx.x;
    const int tid = threadIdx.x;

    __shared__ float Wl[KO][IN + 1];   // padded: stride 9 -> conflict-free
    __shared__ float xsl[B][IN];       // 8 KB
    __shared__ float red[256][C_];     // 10 KB

    for (int idx = tid; idx < KO * IN; idx += 256)
        Wl[idx >> 3][idx & 7] = W[(size_t)n * (KO * IN) + idx];
    for (int idx = tid; idx < B * IN / 4; idx += 256) {   // 512 float4
        int bb = idx >> 1, r = idx & 1;
        *(float4*)(&xsl[bb][r * 4]) = *(const float4*)(x + (size_t)bb * (N * IN) + (size_t)n * IN + r * 4);
    }
    __syncthreads();

    const int o = tid & 15;
    const int blane = tid >> 4;

    float part[C_];
#pragma unroll
    for (int k = 0; k < C_; ++k) part[k] = 0.f;

    for (int t = 0; t < B / 16; ++t) {
        int bb = blane + t * 16;
        float xv[IN];
#pragma unroll
        for (int i = 0; i < IN; ++i) xv[i] = xsl[bb][i];
        const float* vb = v + (size_t)bb * KO + o;
#pragma unroll
        for (int k = 0; k < C_; ++k) {
            const float* wp = &Wl[k * OUT + o][0];
            float d = 0.f;
#pragma unroll
            for (int i = 0; i < IN; ++i) d += wp[i] * xv[i];
            part[k] += d * vb[k * OUT];
        }
    }

#pragma unroll
    for (int k = 0; k < C_; ++k) red[tid][k] = part[k];
    __syncthreads();
    for (int off = 128; off > 0; off >>= 1) {
        if (tid < off) {
#pragma unroll
            for (int k = 0; k < C_; ++k) red[tid][k] += red[tid + off][k];
        }
        __syncthreads();
    }
    if (tid < C_) {
        float a = red[0][tid] * (1.0f / B);
        float* bp = bij + (size_t)n * C_ + tid;
        *bp = accumulate ? (*bp + a) : a;
    }
}

// ---------------- softmax over k (10) per n
__global__ __launch_bounds__(256) void k_softmax(
    const float* __restrict__ bij, float* __restrict__ c)
{
    int n = blockIdx.x * 256 + threadIdx.x;
    if (n >= N) return;
    float b[C_], m = -1e30f;
#pragma unroll
    for (int k = 0; k < C_; ++k) { b[k] = bij[(size_t)n * C_ + k]; m = fmaxf(m, b[k]); }
    float s = 0.f;
#pragma unroll
    for (int k = 0; k < C_; ++k) { float e = __expf(b[k] - m); b[k] = e; s += e; }
    float inv = 1.f / s;
#pragma unroll
    for (int k = 0; k < C_; ++k) c[(size_t)n * C_ + k] = b[k] * inv;
}

extern "C" void kernel_launch(void* const* d_in, const int* in_sizes, int n_in,
                              void* d_out, int out_size, void* d_ws, size_t ws_size,
                              hipStream_t stream)
{
    const float* x = (const float*)d_in[0];   // [B, N, IN]
    const float* W = (const float*)d_in[1];   // [1, N, C, OUT, IN]
    float* out = (float*)d_out;               // [B, C, OUT, 1] = 40960 floats
    float* ws  = (float*)d_ws;

    float* part = ws;                         // 192 * 40960 = 7864320 floats (31.5 MB)
    float* bij  = ws + 7864320;               // 11520
    float* c    = bij + 11520;                // 11520
    float* v    = c + 11520;                  // 40960

    const int GS = 3072;

    // iteration 0: c = 1/C exactly (softmax of zeros); b_ij = a (write mode)
    k_s_partial<<<GS, 64, 0, stream>>>(x, W, nullptr, part);
    k_reduce_squash<<<640, 256, 0, stream>>>(part, v, nullptr);
    k_a<<<N, 256, 0, stream>>>(x, W, v, bij, 0);

    // iteration 1
    k_softmax<<<5, 256, 0, stream>>>(bij, c);
    k_s_partial<<<GS, 64, 0, stream>>>(x, W, c, part);
    k_reduce_squash<<<640, 256, 0, stream>>>(part, v, nullptr);
    k_a<<<N, 256, 0, stream>>>(x, W, v, bij, 1);

    // iteration 2 (final: write d_out)
    k_softmax<<<5, 256, 0, stream>>>(bij, c);
    k_s_partial<<<GS, 64, 0, stream>>>(x, W, c, part);
    k_reduce_squash<<<640, 256, 0, stream>>>(part, v, out);
}

// Round 10
// 141.163 us; speedup vs baseline: 2.2704x; 2.2704x over previous
//
#include <hip/hip_runtime.h>
#include <math.h>

#define B 256
#define N 1152
#define C_ 10
#define OUT 16
#define IN 8
#define KO 160          // C_*OUT

// ---- s-partial geometry: 64-thread (1-wave) blocks, BT=4 rows/thread, KG=5 capsules
#define MB 16           // batch rows per block
#define NC 9            // n per chunk
#define NCH 128         // N/NC  -> partial slab 21 MB (2.6 MB/XCD: R9 showed >this thrashes L2)
#define KG 5            // capsules per block (2 k-groups)
#define XSTR 84         // padded row stride (floats) — proven conflict-free in R7

// partial[ch][b][k*16+o] = sum_{n in chunk} c[n,k]*(W[n,k,o,:].x[b,n,:])
// grid 4096 = 8 XCD * 16 ch * 2 kg * 16 bt (bt fastest: 16 blocks share one 23KB W
// half-chunk on one XCD). 16 one-wave blocks/CU = 4 waves/SIMD (R7 had only 2).
__global__ __launch_bounds__(64, 4) void k_s_partial(
    const float* __restrict__ x, const float* __restrict__ W,
    const float* __restrict__ c, float* __restrict__ partial)
{
    __shared__ float xs[MB][XSTR];      // 5.4 KB
    __shared__ float cs[NC][KG];        // 180 B

    const int tid = threadIdx.x;        // 0..63
    const int id  = blockIdx.x;
    const int g   = id & 7;             // XCD
    const int q   = id >> 3;            // 0..511
    const int bt  = q & 15;             // b-tile fastest on XCD -> W reuse
    const int kg  = (q >> 4) & 1;       // k-group
    const int chl = q >> 5;             // 0..15
    const int ch  = g * 16 + chl;       // 0..127
    const int b0  = bt * MB;
    const int n0  = ch * NC;
    const int k0  = kg * KG;

    // stage x tile: 16 rows x 18 float4 (72 contiguous floats each)
    for (int idx = tid; idx < MB * 18; idx += 64) {
        int bl = idx / 18, r = idx - bl * 18;
        float4 val = *(const float4*)(x + (size_t)(b0 + bl) * (N * IN) + (size_t)n0 * IN + r * 4);
        *(float4*)(&xs[bl][r * 4]) = val;
    }
    if (c) {
        for (int idx = tid; idx < NC * KG; idx += 64) {
            int nl = idx / KG, kk = idx - nl * KG;
            cs[nl][kk] = c[(size_t)(n0 + nl) * C_ + (k0 + kk)];
        }
    }
    __syncthreads();

    const int o   = tid & 15;
    const int grp = (tid >> 4) * 4;     // rows grp..grp+3

    float acc[4][KG];
#pragma unroll
    for (int r = 0; r < 4; ++r)
#pragma unroll
        for (int kk = 0; kk < KG; ++kk) acc[r][kk] = 0.f;

    const float* Wb = W + (size_t)n0 * (KO * IN) + (size_t)(k0 * OUT + o) * IN;

    for (int nl = 0; nl < NC; ++nl) {
        float4 xr[4][2];
#pragma unroll
        for (int r = 0; r < 4; ++r) {
            xr[r][0] = *(const float4*)(&xs[grp + r][nl * IN]);
            xr[r][1] = *(const float4*)(&xs[grp + r][nl * IN + 4]);
        }
        float cw[KG];
#pragma unroll
        for (int kk = 0; kk < KG; ++kk) cw[kk] = c ? cs[nl][kk] : 0.1f;

        const float* Wn = Wb + (size_t)nl * (KO * IN);
#pragma unroll
        for (int kk = 0; kk < KG; ++kk) {
            float4 w0 = *(const float4*)(Wn + kk * (OUT * IN));
            float4 w1 = *(const float4*)(Wn + kk * (OUT * IN) + 4);
#pragma unroll
            for (int r = 0; r < 4; ++r) {
                float d = w0.x * xr[r][0].x + w0.y * xr[r][0].y
                        + w0.z * xr[r][0].z + w0.w * xr[r][0].w
                        + w1.x * xr[r][1].x + w1.y * xr[r][1].y
                        + w1.z * xr[r][1].z + w1.w * xr[r][1].w;
                acc[r][kk] += cw[kk] * d;
            }
        }
    }

#pragma unroll
    for (int r = 0; r < 4; ++r) {
        float* pp = partial + (size_t)ch * (B * KO) + (size_t)(b0 + grp + r) * KO
                  + (size_t)k0 * OUT + o;
#pragma unroll
        for (int kk = 0; kk < KG; ++kk) pp[kk * OUT] = acc[r][kk];
    }
}

// ---------------- reduce partials over 128 chunks + squash (R7 proven)
__global__ __launch_bounds__(256) void k_reduce_squash(
    const float* __restrict__ partial, float* __restrict__ v, float* __restrict__ out)
{
    __shared__ float red[256];
    const int tid = threadIdx.x;
    const int e   = blockIdx.x * 64 + (tid & 63);   // element 0..40959
    const int q   = tid >> 6;                       // wave 0..3
    float s = 0.f;
#pragma unroll
    for (int i = 0; i < NCH / 4; ++i)
        s += partial[(size_t)(q * (NCH / 4) + i) * (B * KO) + e];
    red[tid] = s;
    __syncthreads();
    if (q == 0) {
        s = red[tid] + red[tid + 64] + red[tid + 128] + red[tid + 192];
        float vv = s * fabsf(s) / (1.f + s * s);
        v[e] = vv;
        if (out) out[e] = vv;
    }
}

// ---------------- a-pass (R6 proven version): bij[n][k] (+)= (1/B) sum_{b,o} (W.x)*v
__global__ __launch_bounds__(256) void k_a(
    const float* __restrict__ x, const float* __restrict__ W,
    const float* __restrict__ v, float* __restrict__ bij, int accumulate)
{
    const int n = blockIdx.x;
    const int tid = threadIdx.x;

    __shared__ float Wl[KO][IN + 1];   // padded: stride 9 -> conflict-free
    __shared__ float xsl[B][IN];       // 8 KB
    __shared__ float red[256][C_];     // 10 KB

    for (int idx = tid; idx < KO * IN; idx += 256)
        Wl[idx >> 3][idx & 7] = W[(size_t)n * (KO * IN) + idx];
    for (int idx = tid; idx < B * IN / 4; idx += 256) {   // 512 float4
        int bb = idx >> 1, r = idx & 1;
        *(float4*)(&xsl[bb][r * 4]) = *(const float4*)(x + (size_t)bb * (N * IN) + (size_t)n * IN + r * 4);
    }
    __syncthreads();

    const int o = tid & 15;
    const int blane = tid >> 4;

    float part[C_];
#pragma unroll
    for (int k = 0; k < C_; ++k) part[k] = 0.f;

    for (int t = 0; t < B / 16; ++t) {
        int bb = blane + t * 16;
        float xv[IN];
#pragma unroll
        for (int i = 0; i < IN; ++i) xv[i] = xsl[bb][i];
        const float* vb = v + (size_t)bb * KO + o;
#pragma unroll
        for (int k = 0; k < C_; ++k) {
            const float* wp = &Wl[k * OUT + o][0];
            float d = 0.f;
#pragma unroll
            for (int i = 0; i < IN; ++i) d += wp[i] * xv[i];
            part[k] += d * vb[k * OUT];
        }
    }

#pragma unroll
    for (int k = 0; k < C_; ++k) red[tid][k] = part[k];
    __syncthreads();
    for (int off = 128; off > 0; off >>= 1) {
        if (tid < off) {
#pragma unroll
            for (int k = 0; k < C_; ++k) red[tid][k] += red[tid + off][k];
        }
        __syncthreads();
    }
    if (tid < C_) {
        float a = red[0][tid] * (1.0f / B);
        float* bp = bij + (size_t)n * C_ + tid;
        *bp = accumulate ? (*bp + a) : a;
    }
}

// ---------------- softmax over k (10) per n
__global__ __launch_bounds__(256) void k_softmax(
    const float* __restrict__ bij, float* __restrict__ c)
{
    int n = blockIdx.x * 256 + threadIdx.x;
    if (n >= N) return;
    float b[C_], m = -1e30f;
#pragma unroll
    for (int k = 0; k < C_; ++k) { b[k] = bij[(size_t)n * C_ + k]; m = fmaxf(m, b[k]); }
    float s = 0.f;
#pragma unroll
    for (int k = 0; k < C_; ++k) { float e = __expf(b[k] - m); b[k] = e; s += e; }
    float inv = 1.f / s;
#pragma unroll
    for (int k = 0; k < C_; ++k) c[(size_t)n * C_ + k] = b[k] * inv;
}

extern "C" void kernel_launch(void* const* d_in, const int* in_sizes, int n_in,
                              void* d_out, int out_size, void* d_ws, size_t ws_size,
                              hipStream_t stream)
{
    const float* x = (const float*)d_in[0];   // [B, N, IN]
    const float* W = (const float*)d_in[1];   // [1, N, C, OUT, IN]
    float* out = (float*)d_out;               // [B, C, OUT, 1] = 40960 floats
    float* ws  = (float*)d_ws;

    float* part = ws;                         // 128 * 40960 = 5242880 floats (21 MB)
    float* bij  = ws + 5242880;               // 11520
    float* c    = bij + 11520;                // 11520
    float* v    = c + 11520;                  // 40960

    const int GS = 4096;                      // 8 XCD * 16 ch * 2 kg * 16 bt

    // iteration 0: c = 1/C exactly (softmax of zeros); b_ij = a (write mode)
    k_s_partial<<<GS, 64, 0, stream>>>(x, W, nullptr, part);
    k_reduce_squash<<<640, 256, 0, stream>>>(part, v, nullptr);
    k_a<<<N, 256, 0, stream>>>(x, W, v, bij, 0);

    // iteration 1
    k_softmax<<<5, 256, 0, stream>>>(bij, c);
    k_s_partial<<<GS, 64, 0, stream>>>(x, W, c, part);
    k_reduce_squash<<<640, 256, 0, stream>>>(part, v, nullptr);
    k_a<<<N, 256, 0, stream>>>(x, W, v, bij, 1);

    // iteration 2 (final: write d_out)
    k_softmax<<<5, 256, 0, stream>>>(bij, c);
    k_s_partial<<<GS, 64, 0, stream>>>(x, W, c, part);
    k_reduce_squash<<<640, 256, 0, stream>>>(part, v, out);
}

// Round 11
// 131.272 us; speedup vs baseline: 2.4415x; 1.0753x over previous
//
#include <hip/hip_runtime.h>
#include <math.h>

#define B 256
#define N 1152
#define C_ 10
#define OUT 16
#define IN 8
#define KO 160          // C_*OUT

// ---- s-partial geometry (R10 proven): 64-thread blocks, BT=4, KG=5, grid 4096
#define MB 16
#define NC 9
#define NCH 128         // partial slab 21 MB (R9: bigger thrashes per-XCD L2)
#define KG 5
#define XSTR 84

// partial[ch][b][k*16+o] = sum_{n in chunk} c[n,k]*(W[n,k,o,:].x[b,n,:])
__global__ __launch_bounds__(64, 4) void k_s_partial(
    const float* __restrict__ x, const float* __restrict__ W,
    const float* __restrict__ c, float* __restrict__ partial)
{
    __shared__ float xs[MB][XSTR];
    __shared__ float cs[NC][KG];

    const int tid = threadIdx.x;
    const int id  = blockIdx.x;
    const int g   = id & 7;
    const int q   = id >> 3;
    const int bt  = q & 15;
    const int kg  = (q >> 4) & 1;
    const int chl = q >> 5;
    const int ch  = g * 16 + chl;
    const int b0  = bt * MB;
    const int n0  = ch * NC;
    const int k0  = kg * KG;

    for (int idx = tid; idx < MB * 18; idx += 64) {
        int bl = idx / 18, r = idx - bl * 18;
        float4 val = *(const float4*)(x + (size_t)(b0 + bl) * (N * IN) + (size_t)n0 * IN + r * 4);
        *(float4*)(&xs[bl][r * 4]) = val;
    }
    if (c) {
        for (int idx = tid; idx < NC * KG; idx += 64) {
            int nl = idx / KG, kk = idx - nl * KG;
            cs[nl][kk] = c[(size_t)(n0 + nl) * C_ + (k0 + kk)];
        }
    }
    __syncthreads();

    const int o   = tid & 15;
    const int grp = (tid >> 4) * 4;

    float acc[4][KG];
#pragma unroll
    for (int r = 0; r < 4; ++r)
#pragma unroll
        for (int kk = 0; kk < KG; ++kk) acc[r][kk] = 0.f;

    const float* Wb = W + (size_t)n0 * (KO * IN) + (size_t)(k0 * OUT + o) * IN;

    for (int nl = 0; nl < NC; ++nl) {
        // batch ALL W loads for this nl into registers first (R10 VGPR=64 showed the
        // compiler trickled these 2-at-a-time; explicit batch keeps 10 loads in flight)
        const float* Wn = Wb + (size_t)nl * (KO * IN);
        float4 w[KG][2];
#pragma unroll
        for (int kk = 0; kk < KG; ++kk) {
            w[kk][0] = *(const float4*)(Wn + kk * (OUT * IN));
            w[kk][1] = *(const float4*)(Wn + kk * (OUT * IN) + 4);
        }
        float4 xr[4][2];
#pragma unroll
        for (int r = 0; r < 4; ++r) {
            xr[r][0] = *(const float4*)(&xs[grp + r][nl * IN]);
            xr[r][1] = *(const float4*)(&xs[grp + r][nl * IN + 4]);
        }
        float cw[KG];
#pragma unroll
        for (int kk = 0; kk < KG; ++kk) cw[kk] = c ? cs[nl][kk] : 0.1f;

#pragma unroll
        for (int kk = 0; kk < KG; ++kk) {
#pragma unroll
            for (int r = 0; r < 4; ++r) {
                float d = w[kk][0].x * xr[r][0].x + w[kk][0].y * xr[r][0].y
                        + w[kk][0].z * xr[r][0].z + w[kk][0].w * xr[r][0].w
                        + w[kk][1].x * xr[r][1].x + w[kk][1].y * xr[r][1].y
                        + w[kk][1].z * xr[r][1].z + w[kk][1].w * xr[r][1].w;
                acc[r][kk] += cw[kk] * d;
            }
        }
    }

#pragma unroll
    for (int r = 0; r < 4; ++r) {
        float* pp = partial + (size_t)ch * (B * KO) + (size_t)(b0 + grp + r) * KO
                  + (size_t)k0 * OUT + o;
#pragma unroll
        for (int kk = 0; kk < KG; ++kk) pp[kk * OUT] = acc[r][kk];
    }
}

// ---------------- reduce partials over 128 chunks + squash (proven)
__global__ __launch_bounds__(256) void k_reduce_squash(
    const float* __restrict__ partial, float* __restrict__ v, float* __restrict__ out)
{
    __shared__ float red[256];
    const int tid = threadIdx.x;
    const int e   = blockIdx.x * 64 + (tid & 63);
    const int q   = tid >> 6;
    float s = 0.f;
#pragma unroll
    for (int i = 0; i < NCH / 4; ++i)
        s += partial[(size_t)(q * (NCH / 4) + i) * (B * KO) + e];
    red[tid] = s;
    __syncthreads();
    if (q == 0) {
        s = red[tid] + red[tid + 64] + red[tid + 128] + red[tid + 192];
        float vv = s * fabsf(s) / (1.f + s * s);
        v[e] = vv;
        if (out) out[e] = vv;
    }
}

// ---------------- x transpose: xt[n][b][i] = x[b][n][i]  (x is iteration-invariant; paid once)
// grid 288 = 8 b-tiles x 36 n-tiles; LDS-tiled, coalesced read AND write.
__global__ __launch_bounds__(256) void k_xT(
    const float* __restrict__ x, float* __restrict__ xt)
{
    __shared__ float t[32][32 * IN + 4];   // 32 x 260 floats = 33.3 KB
    const int bb0 = (blockIdx.x & 7) * 32;
    const int nn0 = (blockIdx.x >> 3) * 32;

    for (int idx = threadIdx.x; idx < 32 * 64; idx += 256) {
        int b = idx >> 6, r = idx & 63;
        float4 val = *(const float4*)(x + (size_t)(bb0 + b) * (N * IN) + (size_t)nn0 * IN + r * 4);
        *(float4*)(&t[b][r * 4]) = val;
    }
    __syncthreads();
    for (int idx = threadIdx.x; idx < 32 * 64; idx += 256) {
        int n = idx >> 6, r = idx & 63;
        int b = r >> 1, i = (r & 1) * 4;
        float4 val = *(const float4*)(&t[b][n * IN + i]);
        *(float4*)(xt + (size_t)(nn0 + n) * (B * IN) + (size_t)(bb0 + b) * IN + i) = val;
    }
}

// ---------------- a-pass + fused softmax, x from TRANSPOSED xt (coalesced staging):
// bij[n][k] (+)= (1/B) sum_{b,o} (W[n,k,o,:].x[b,n,:]) * v[b,k,o];  c = softmax(bij[n][:])
__global__ __launch_bounds__(256) void k_a_sm(
    const float* __restrict__ xt, const float* __restrict__ W,
    const float* __restrict__ v, float* __restrict__ bij,
    float* __restrict__ c_out, int accumulate)
{
    const int n = blockIdx.x;
    const int tid = threadIdx.x;

    __shared__ float Wl[KO][IN + 1];
    __shared__ float xtl[B][IN];
    __shared__ float red[4][16][C_];
    __shared__ float bnew[C_];

    for (int idx = tid; idx < KO * IN; idx += 256)
        Wl[idx >> 3][idx & 7] = W[(size_t)n * (KO * IN) + idx];
    // coalesced: xt[n] is 2048 contiguous floats
    {
        const float4* src = (const float4*)(xt + (size_t)n * (B * IN));
        for (int idx = tid; idx < B * IN / 4; idx += 256)
            *(float4*)(&xtl[idx >> 1][(idx & 1) * 4]) = src[idx];
    }
    __syncthreads();

    const int o = tid & 15;
    const int blane = tid >> 4;

    float part[C_];
#pragma unroll
    for (int k = 0; k < C_; ++k) part[k] = 0.f;

    for (int t = 0; t < B / 16; ++t) {
        int bb = blane + t * 16;
        float4 xv0 = *(const float4*)(&xtl[bb][0]);
        float4 xv1 = *(const float4*)(&xtl[bb][4]);
        const float* vb = v + (size_t)bb * KO + o;
        float vv[C_];
#pragma unroll
        for (int k = 0; k < C_; ++k) vv[k] = vb[k * OUT];
#pragma unroll
        for (int k = 0; k < C_; ++k) {
            const float* wp = &Wl[k * OUT + o][0];
            float d = wp[0] * xv0.x + wp[1] * xv0.y + wp[2] * xv0.z + wp[3] * xv0.w
                    + wp[4] * xv1.x + wp[5] * xv1.y + wp[6] * xv1.z + wp[7] * xv1.w;
            part[k] += d * vv[k];
        }
    }

    // reduce over the 4 blane groups in each wave, then across waves via LDS
    const int wv = tid >> 6;
#pragma unroll
    for (int k = 0; k < C_; ++k) {
        float p = part[k];
        p += __shfl_xor(p, 16);
        p += __shfl_xor(p, 32);
        part[k] = p;
    }
    if ((tid & 63) < 16) {
#pragma unroll
        for (int k = 0; k < C_; ++k) red[wv][o][k] = part[k];
    }
    __syncthreads();

    if (tid < C_) {
        float a = 0.f;
#pragma unroll
        for (int w = 0; w < 4; ++w)
#pragma unroll
            for (int oo = 0; oo < 16; ++oo) a += red[w][oo][tid];
        a *= (1.0f / B);
        float bo = accumulate ? bij[(size_t)n * C_ + tid] : 0.f;
        float bn = bo + a;
        bij[(size_t)n * C_ + tid] = bn;
        bnew[tid] = bn;
    }
    __syncthreads();
    if (tid < C_) {
        float m = -1e30f;
#pragma unroll
        for (int k = 0; k < C_; ++k) m = fmaxf(m, bnew[k]);
        float ssum = 0.f;
#pragma unroll
        for (int k = 0; k < C_; ++k) ssum += __expf(bnew[k] - m);
        c_out[(size_t)n * C_ + tid] = __expf(bnew[tid] - m) / ssum;
    }
}

extern "C" void kernel_launch(void* const* d_in, const int* in_sizes, int n_in,
                              void* d_out, int out_size, void* d_ws, size_t ws_size,
                              hipStream_t stream)
{
    const float* x = (const float*)d_in[0];   // [B, N, IN]
    const float* W = (const float*)d_in[1];   // [1, N, C, OUT, IN]
    float* out = (float*)d_out;               // [B, C, OUT, 1] = 40960 floats
    float* ws  = (float*)d_ws;

    float* part = ws;                         // 128 * 40960 = 5242880 floats (21 MB)
    float* bij  = ws + 5242880;               // 11520
    float* c    = bij + 11520;                // 11520
    float* v    = c + 11520;                  // 40960
    float* xt   = v + 40960;                  // 2359296 floats (9.4 MB)

    const int GS = 4096;

    k_xT<<<288, 256, 0, stream>>>(x, xt);

    // iteration 0: c = 1/C exactly (softmax of zeros)
    k_s_partial<<<GS, 64, 0, stream>>>(x, W, nullptr, part);
    k_reduce_squash<<<640, 256, 0, stream>>>(part, v, nullptr);
    k_a_sm<<<N, 256, 0, stream>>>(xt, W, v, bij, c, 0);

    // iteration 1
    k_s_partial<<<GS, 64, 0, stream>>>(x, W, c, part);
    k_reduce_squash<<<640, 256, 0, stream>>>(part, v, nullptr);
    k_a_sm<<<N, 256, 0, stream>>>(xt, W, v, bij, c, 1);

    // iteration 2 (final: write d_out)
    k_s_partial<<<GS, 64, 0, stream>>>(x, W, c, part);
    k_reduce_squash<<<640, 256, 0, stream>>>(part, v, out);
}